// Round 1
// 92.945 us; speedup vs baseline: 1.0423x; 1.0423x over previous
//
#include <hip/hip_runtime.h>

// ---------------------------------------------------------------------------
// PolyDecoder: out[4096,64] = polyfeats(z)[4096,37449] @ W^T + b
// f16 MFMA GEMM, A generated on the fly from registers; B double-banked in
// REGISTERS with 8-step-deep prefetch (~1300 cyc cover) — no barriers in the
// K-loop. Two-phase output (nontemporal partial stores + reduce), no atomics.
//
// Padded K layout (32-granular; W padded with zeros):
//   kpad [0,8)=z | 8=const(bias folded) | [9,32)=0 | [32,96)=z^2 |
//   [96,608)=z^3 | [608,4704)=z^4 | [4704,37472)=z^5 | [37472,37504)=0
// step s = kpad/32: 0 deg<=1 | 1..2 deg2 | 3..18 deg3 | 19..146 deg4 |
//                   147..1170 deg5 | 1171 pad
//
// Grid (mb-major): (MBLK=32 m-blocks of 128 rows) x (KY=16) = 512 blocks
//   == exactly 2 blocks/CU on 256 CUs -> single dispatch round, no tail.
// Every block ky in [0,16) does a uniform 9-group pipeline + 1-2 extra steps:
//   groups 0..7: deg5 slice, s = 147 + 64*ky          (64 steps)
//   group  8:    deg4 slice, s = 19 + 8*ky            (8 steps)
//   extras:      s = ky, and s = 16+ky for ky < 3     (1-2 steps)
// Block: 4 waves; wave (g=w>>1, h=w&1): rows [g*64,+64) x cols [h*32,+32)
//   -> 8 mfma_f32_16x16x32_f16 / step; acc 4x2xf32x4 = 32 VGPR.
// B regs: Bk[2][16] half8 = 128 VGPR; ~210 total -> 2 waves/SIMD.
// ---------------------------------------------------------------------------

#define TOTAL_TERMS 37449
#define NSTEP 1172
#define MBLK 32
#define KY 16
#define OUT_ELEMS 262144            // 4096*64

typedef _Float16 half8 __attribute__((ext_vector_type(8)));
typedef float f32x4 __attribute__((ext_vector_type(4)));

// Coalesced tiled transpose W (f32, n-major) -> Wt (f16 fragments).
// Fragment element (s,nt,lane,j) = W[nt*16+(lane&15)][orig(s*32+(lane>>4)*8+j)]
__global__ __launch_bounds__(256) void convert_w(const float* __restrict__ W,
                                                 const float* __restrict__ bias,
                                                 _Float16* __restrict__ Wt) {
    __shared__ _Float16 lds[64][72];
    int tid  = threadIdx.x;
    int lane = tid & 63;
    int nq   = tid >> 6;               // 0..3
    int kb   = blockIdx.x * 64;
    int kp   = kb + lane;

    int o, mode;                       // 0=load W, 1=zero, 2=const+bias
    if (kp < 8)           { o = 1 + kp;            mode = 0; }
    else if (kp == 8)     { o = 0;                 mode = 2; }
    else if (kp < 32)     { o = 0;                 mode = 1; }
    else if (kp < 96)     { o = 9    + (kp - 32);  mode = 0; }
    else if (kp < 608)    { o = 73   + (kp - 96);  mode = 0; }
    else if (kp < 4704)   { o = 585  + (kp - 608); mode = 0; }
    else if (kp < 37472)  { o = 4681 + (kp - 4704);mode = 0; }
    else                  { o = 0;                 mode = 1; }

#pragma unroll
    for (int r = 0; r < 16; ++r) {
        int n = r * 4 + nq;
        const float* wrow = W + (size_t)n * TOTAL_TERMS;
        float v;
        if (mode == 1)      v = 0.f;
        else if (mode == 2) v = wrow[0] + bias[n];
        else                v = wrow[o];             // coalesced along lane
        lds[n][lane] = (_Float16)v;
    }
    __syncthreads();

    int quad = lane >> 4, l16 = lane & 15;
    int n = nq * 16 + l16;
#pragma unroll
    for (int sl = 0; sl < 2; ++sl) {
        int kk = sl * 32 + quad * 8;
        half8 hv;
#pragma unroll
        for (int j = 0; j < 8; ++j) hv[j] = lds[n][kk + j];
        int s = (kb >> 5) + sl;
        *(half8*)(Wt + ((size_t)(s * 4 + nq) * 64 + lane) * 8) = hv;  // coalesced
    }
}

__global__ __launch_bounds__(256, 2) void poly_gemm(const float* __restrict__ z,
                                                    const _Float16* __restrict__ Wt,
                                                    float* __restrict__ part,
                                                    float* __restrict__ out,
                                                    int use_atomic) {
    __shared__ __align__(16) _Float16 zm[128][8];   // sample-major
    __shared__ _Float16 zT[8][144];                 // digit-major

    int tid  = threadIdx.x;
    int lane = tid & 63;
    int w    = tid >> 6;
    int g    = w >> 1;                 // rows [g*64, g*64+64)
    int h    = w & 1;                  // cols [h*32, h*32+32)
    int mb   = blockIdx.x;
    int ky   = blockIdx.y;             // [0, 16) -- every block is uniform

    // Per-step B bytes: 4 frags x 1024 B; this wave reads frags 2h, 2h+1.
    const char* gb  = (const char*)Wt + (size_t)((147 + 64 * ky) * 4 + 2 * h) * 1024
                    + (size_t)lane * 16;                       // deg5 slice
    const char* gb4 = (const char*)Wt + (size_t)((19 + 8 * ky) * 4 + 2 * h) * 1024
                    + (size_t)lane * 16;                       // deg4 slice

    // Prologue: prefetch deg5 group 0 (8 steps) into bank 0 BEFORE z staging
    // so its latency overlaps the z loads + barrier.
    half8 Bk[2][16];
#pragma unroll
    for (int ii = 0; ii < 8; ++ii)
#pragma unroll
        for (int k = 0; k < 2; ++k)
            Bk[0][ii * 2 + k] = *(const half8*)(gb + ii * 4096 + k * 1024);

    if (tid < 128) {
        const float* zp = z + ((size_t)(mb * 128 + tid)) * 8;
        float4 a = *(const float4*)zp;
        float4 b4 = *(const float4*)(zp + 4);
        half8 hz;
        hz[0] = (_Float16)a.x;  hz[1] = (_Float16)a.y;
        hz[2] = (_Float16)a.z;  hz[3] = (_Float16)a.w;
        hz[4] = (_Float16)b4.x; hz[5] = (_Float16)b4.y;
        hz[6] = (_Float16)b4.z; hz[7] = (_Float16)b4.w;
        *(half8*)&zm[tid][0] = hz;
#pragma unroll
        for (int j = 0; j < 8; ++j) zT[j][tid] = hz[j];
    }
    __syncthreads();

    int quad = lane >> 4;
    int l16  = lane & 15;
    int mrow[4];
    half8 zv[4];
    _Float16 zq[4], zq4[4];
#pragma unroll
    for (int t = 0; t < 4; ++t) {
        mrow[t] = g * 64 + t * 16 + l16;
        zv[t]   = *(const half8*)&zm[mrow[t]][0];
        zq[t]   = zT[quad][mrow[t]];       // z[quad]
        zq4[t]  = zT[quad + 4][mrow[t]];   // z[quad+4]
    }

    f32x4 acc[4][2];
#pragma unroll
    for (int t = 0; t < 4; ++t)
#pragma unroll
        for (int k = 0; k < 2; ++k) acc[t][k] = (f32x4){0.f, 0.f, 0.f, 0.f};

    // d1 digit for both deg5 and deg4 slices of this ky: z[ky>>1]
    _Float16 a1[4];
#pragma unroll
    for (int t = 0; t < 4; ++t) a1[t] = zT[ky >> 1][mrow[t]];

    // ---- deg5 main: 8 groups (4 sc x 2 gp), bank = group & 1 ----
    for (int sc = 0; sc < 4; ++sc) {
        int rtop = (4 * ky + sc) & 7;                  // d2 digit
        _Float16 gz[4];
#pragma unroll
        for (int t = 0; t < 4; ++t) gz[t] = a1[t] * zT[rtop][mrow[t]];
#pragma unroll
        for (int gp = 0; gp < 2; ++gp) {
            // prefetch next 8-step group into the other bank; the 9th group
            // slot fetches the deg4 slice instead of running off the end
            const char* gn = (sc == 3 && gp == 1) ? gb4 : (gb + 32768);
#pragma unroll
            for (int ii = 0; ii < 8; ++ii)
#pragma unroll
                for (int k = 0; k < 2; ++k)
                    Bk[gp ^ 1][ii * 2 + k] =
                        *(const half8*)(gn + ii * 4096 + k * 1024);
            // compute 8 steps from current bank (all indices compile-time)
#pragma unroll
            for (int ii = 0; ii < 8; ++ii) {
                const int r3 = gp * 4 + (ii >> 1);
                half8 av[4];
#pragma unroll
                for (int t = 0; t < 4; ++t) {
                    _Float16 f = gz[t] * zv[t][r3] *
                                 ((ii & 1) ? zq4[t] : zq[t]);
#pragma unroll
                    for (int e = 0; e < 8; ++e) av[t][e] = zv[t][e] * f;
                }
#pragma unroll
                for (int t = 0; t < 4; ++t)
#pragma unroll
                    for (int k = 0; k < 2; ++k)
                        acc[t][k] = __builtin_amdgcn_mfma_f32_16x16x32_f16(
                            av[t], Bk[gp][ii * 2 + k], acc[t][k], 0, 0, 0);
            }
            gb += 32768;
        }
    }

    // ---- deg4 group: 8 steps from bank 0; prefetch extra-step B -> bank 1 ----
    {
        const char* ge0 = (const char*)Wt + (size_t)(ky * 4 + 2 * h) * 1024
                        + (size_t)lane * 16;           // step s = ky
        Bk[1][0] = *(const half8*)(ge0);
        Bk[1][1] = *(const half8*)(ge0 + 1024);
        if (ky < 3) {                                  // step s = 16 + ky
            const char* ge1 = (const char*)Wt
                            + (size_t)((16 + ky) * 4 + 2 * h) * 1024
                            + (size_t)lane * 16;
            Bk[1][2] = *(const half8*)(ge1);
            Bk[1][3] = *(const half8*)(ge1 + 1024);
        }
        // deg4 digits: d1 = ky>>1 (a1), d2 = (ky&1)*4 + (ii>>1),
        //              d3 = quad + 4*(ii&1), d4 = e
        const int r3b = (ky & 1) * 4;
        _Float16 d2z[4][4];                            // static-index regs
#pragma unroll
        for (int j = 0; j < 4; ++j)
#pragma unroll
            for (int t = 0; t < 4; ++t) d2z[t][j] = zT[r3b + j][mrow[t]];
#pragma unroll
        for (int ii = 0; ii < 8; ++ii) {
            half8 av[4];
#pragma unroll
            for (int t = 0; t < 4; ++t) {
                _Float16 f = a1[t] * d2z[t][ii >> 1] *
                             ((ii & 1) ? zq4[t] : zq[t]);
#pragma unroll
                for (int e = 0; e < 8; ++e) av[t][e] = zv[t][e] * f;
            }
#pragma unroll
            for (int t = 0; t < 4; ++t)
#pragma unroll
                for (int k = 0; k < 2; ++k)
                    acc[t][k] = __builtin_amdgcn_mfma_f32_16x16x32_f16(
                        av[t], Bk[0][ii * 2 + k], acc[t][k], 0, 0, 0);
        }
    }

    // ---- extra low-degree step(s): s = ky, plus s = 16+ky for ky < 3 ----
    {
        half8 av[4];
        if (ky == 0) {
            // s==0: deg<=1 (z | const | zeros)
#pragma unroll
            for (int t = 0; t < 4; ++t) {
                if (quad == 0)      av[t] = zv[t];
                else if (quad == 1) { av[t] = (half8){}; av[t][0] = (_Float16)1.f; }
                else                av[t] = (half8){};
            }
        } else if (ky < 3) {
            // s=1..2: deg2
            int r1 = (ky - 1) * 4 + quad;
#pragma unroll
            for (int t = 0; t < 4; ++t) {
                _Float16 f = zT[r1][mrow[t]];
#pragma unroll
                for (int e = 0; e < 8; ++e) av[t][e] = zv[t][e] * f;
            }
        } else {
            // s=3..15: deg3, u = s-3
            int u = ky - 3;
            int r1 = u >> 1, r2 = ((u & 1) << 2) + quad;
#pragma unroll
            for (int t = 0; t < 4; ++t) {
                _Float16 f = zT[r1][mrow[t]] * zT[r2][mrow[t]];
#pragma unroll
                for (int e = 0; e < 8; ++e) av[t][e] = zv[t][e] * f;
            }
        }
#pragma unroll
        for (int t = 0; t < 4; ++t)
#pragma unroll
            for (int k = 0; k < 2; ++k)
                acc[t][k] = __builtin_amdgcn_mfma_f32_16x16x32_f16(
                    av[t], Bk[1][k], acc[t][k], 0, 0, 0);

        if (ky < 3) {
            // s = 16+ky: deg3, u = 13+ky
            int u = 13 + ky;
            int r1 = u >> 1, r2 = ((u & 1) << 2) + quad;
#pragma unroll
            for (int t = 0; t < 4; ++t) {
                _Float16 f = zT[r1][mrow[t]] * zT[r2][mrow[t]];
#pragma unroll
                for (int e = 0; e < 8; ++e) av[t][e] = zv[t][e] * f;
            }
#pragma unroll
            for (int t = 0; t < 4; ++t)
#pragma unroll
                for (int k = 0; k < 2; ++k)
                    acc[t][k] = __builtin_amdgcn_mfma_f32_16x16x32_f16(
                        av[t], Bk[1][2 + k], acc[t][k], 0, 0, 0);
        }
    }

    // epilogue: C/D layout col=lane&15, row=(lane>>4)*4+reg
    float* dstbase = use_atomic ? out : (part + (size_t)ky * OUT_ELEMS);
#pragma unroll
    for (int t = 0; t < 4; ++t) {
        int mbase = mb * 128 + g * 64 + t * 16 + quad * 4;
#pragma unroll
        for (int k = 0; k < 2; ++k) {
            int col = h * 32 + k * 16 + l16;
#pragma unroll
            for (int r = 0; r < 4; ++r) {
                size_t idx = (size_t)(mbase + r) * 64 + col;
                if (use_atomic) unsafeAtomicAdd(out + idx, acc[t][k][r]);
                else __builtin_nontemporal_store(acc[t][k][r], dstbase + idx);
            }
        }
    }
}

// Phase 2: out[i] = sum_ky part[ky][i]  (vectorized, nontemporal)
__global__ __launch_bounds__(256) void reduce_part(const float* __restrict__ part,
                                                   float* __restrict__ out) {
    int gid = blockIdx.x * 256 + threadIdx.x;      // 65536 float4s
    const f32x4* p4 = (const f32x4*)part;
    f32x4 s = (f32x4){0.f, 0.f, 0.f, 0.f};
#pragma unroll
    for (int j = 0; j < KY; ++j)
        s += __builtin_nontemporal_load(p4 + (size_t)j * (OUT_ELEMS / 4) + gid);
    __builtin_nontemporal_store(s, ((f32x4*)out) + gid);
}

extern "C" void kernel_launch(void* const* d_in, const int* in_sizes, int n_in,
                              void* d_out, int out_size, void* d_ws, size_t ws_size,
                              hipStream_t stream) {
    (void)in_sizes; (void)n_in;
    const float* z = (const float*)d_in[0];
    const float* W = (const float*)d_in[1];
    const float* b = (const float*)d_in[2];
    float* out = (float*)d_out;

    const size_t part_bytes = (size_t)KY * OUT_ELEMS * sizeof(float);  // 16 MB
    const size_t wt_bytes   = (size_t)(NSTEP + 16) * 2048 * sizeof(_Float16);
    const bool two_phase = ws_size >= part_bytes + wt_bytes;

    float* part;
    _Float16* Wt;
    if (two_phase) {
        part = (float*)d_ws;
        Wt   = (_Float16*)((char*)d_ws + part_bytes);
    } else {
        part = out;                    // unused in atomic mode
        Wt   = (_Float16*)d_ws;
    }

    if (!two_phase)
        hipMemsetAsync(d_out, 0, (size_t)out_size * sizeof(float), stream);
    hipLaunchKernelGGL(convert_w, dim3(NSTEP / 2), dim3(256), 0, stream, W, b, Wt);
    hipLaunchKernelGGL(poly_gemm, dim3(MBLK, KY), dim3(256), 0, stream,
                       z, Wt, part, out, two_phase ? 0 : 1);
    if (two_phase)
        hipLaunchKernelGGL(reduce_part, dim3(OUT_ELEMS / 4 / 256), dim3(256), 0,
                           stream, part, out);
}